// Round 5
// baseline (590.030 us; speedup 1.0000x reference)
//
#include <hip/hip_runtime.h>
#include <hip/hip_bf16.h>
#include <stdint.h>

#define B_DIM 16384
#define D_DIM 512
#define INV_T (1.0f / 0.07f)

typedef __bf16 bf16x8 __attribute__((ext_vector_type(8)));
typedef float f32x4 __attribute__((ext_vector_type(4)));

typedef const __attribute__((address_space(1))) void* gptr_t;
typedef __attribute__((address_space(3))) void* lptr_t;

__device__ __forceinline__ uint16_t f32_to_bf16_rne(float x) {
  uint32_t b = __builtin_bit_cast(uint32_t, x);
  b += 0x7FFFu + ((b >> 16) & 1u);
  return (uint16_t)(b >> 16);
}

// One wave per row: load 512 fp32, L2-normalize, write 512 bf16.
__global__ __launch_bounds__(256) void normalize_kernel(const float* __restrict__ in,
                                                        uint16_t* __restrict__ out) {
  int wid = threadIdx.x >> 6;
  int lane = threadIdx.x & 63;
  size_t row = (size_t)blockIdx.x * 4 + wid;
  const float* r = in + row * D_DIM;
  float4 v0 = ((const float4*)r)[lane * 2];
  float4 v1 = ((const float4*)r)[lane * 2 + 1];
  float ssq = v0.x * v0.x + v0.y * v0.y + v0.z * v0.z + v0.w * v0.w +
              v1.x * v1.x + v1.y * v1.y + v1.z * v1.z + v1.w * v1.w;
#pragma unroll
  for (int m = 1; m < 64; m <<= 1) ssq += __shfl_xor(ssq, m);
  float scale = 1.0f / fmaxf(sqrtf(ssq), 1e-12f);
  union {
    uint16_t u[8];
    uint4 v;
  } o;
  o.u[0] = f32_to_bf16_rne(v0.x * scale);
  o.u[1] = f32_to_bf16_rne(v0.y * scale);
  o.u[2] = f32_to_bf16_rne(v0.z * scale);
  o.u[3] = f32_to_bf16_rne(v0.w * scale);
  o.u[4] = f32_to_bf16_rne(v1.x * scale);
  o.u[5] = f32_to_bf16_rne(v1.y * scale);
  o.u[6] = f32_to_bf16_rne(v1.z * scale);
  o.u[7] = f32_to_bf16_rne(v1.w * scale);
  ((uint4*)(out + row * D_DIM))[lane] = o.v;
}

// Persistent-block 256x256-tile NT GEMM. Grid = 256 (1 block/CU); each block
// owns one 256-row brow strip and walks 16 bcol tiles, K-tile pipeline
// (m201-template: m-split halves, st_16x32 swizzle, quadrant phases,
// 1 half staged/phase, one vmcnt(2)/K-tile) running uninterrupted across
// tile boundaries (epilogue overlaps next tile's staging).
__global__ __launch_bounds__(512, 2) void infonce_main(const uint16_t* __restrict__ P,
                                                       const uint16_t* __restrict__ T,
                                                       float* __restrict__ row_sum,
                                                       float* __restrict__ col_sum,
                                                       float* __restrict__ diag) {
  // [dbuf][half(M)][128 rows][64 K-cols], st_16x32 XOR swizzle on content.
  __shared__ __align__(16) uint16_t As[2][2][128][64];  // 64 KB
  __shared__ __align__(16) uint16_t Bs[2][2][128][64];  // 64 KB

  int bid = blockIdx.x;        // 0..255, one per CU
  int xcd = bid & 7;
  int w = bid >> 3;            // 0..31 within XCD
  int br = w & 7;
  int bcg = w >> 3;            // 0..3 bcol-group
  int brow = (xcd * 8 + br) << 8;

  int tid = threadIdx.x;
  int lane = tid & 63;
  int wid = tid >> 6;
  int wr = (wid >> 2) * 128;   // 2 M-wave groups
  int wc = (wid & 3) * 64;     // 4 N-waves
  int rlane = lane >> 4;
  int clane = lane & 15;
  int haA = wid >> 2;          // wave's A half
  int haB = (wid >> 1) & 1;    // wave's B half
  int rbB = (wid & 1) * 64;    // row base within B half
  int swzc = (rlane * 8) ^ ((clane & 4) << 2);  // st_16x32 read swizzle

  f32x4 acc[8][4] = {};

  // Stage one 128x64 half (16 KB): linear LDS dest, inverse-swizzled source.
#define STAGE_HALF(ARR, SRC, ROWBASE, BUF, H, KC)                                \
  do {                                                                           \
    _Pragma("unroll") for (int it = 0; it < 2; ++it) {                           \
      int l = it * 512 + tid;                                                    \
      int r = l >> 3;                                                            \
      int sch = (l & 7) ^ ((r & 4) >> 1);                                        \
      __builtin_amdgcn_global_load_lds(                                          \
          (gptr_t)(SRC + (size_t)((ROWBASE) + (H) * 128 + r) * 512 + (KC) +      \
                   sch * 8),                                                     \
          (lptr_t)(&ARR[BUF][H][0][0] + (size_t)l * 8), 16, 0, 0);               \
    }                                                                            \
  } while (0)

#define RD_A(dst, BUF, MH)                                                       \
  _Pragma("unroll") for (int mq = 0; mq < 4; ++mq)                               \
      _Pragma("unroll") for (int kk = 0; kk < 2; ++kk) dst[mq][kk] =             \
      *(const bf16x8*)(&As[BUF][haA][(MH)*64 + mq * 16 + clane][kk * 32 + swzc])

#define RD_B(dst, BUF, NP)                                                       \
  _Pragma("unroll") for (int np = 0; np < 2; ++np)                               \
      _Pragma("unroll") for (int kk = 0; kk < 2; ++kk) dst[np][kk] =             \
      *(const bf16x8*)(&Bs[BUF][haB][rbB + (NP)*32 + np * 16 + clane]            \
                          [kk * 32 + swzc])

#define MM_Q(MH, NP, aa, bb)                                                     \
  _Pragma("unroll") for (int mq = 0; mq < 4; ++mq)                               \
      _Pragma("unroll") for (int np = 0; np < 2; ++np)                           \
          _Pragma("unroll") for (int kk = 0; kk < 2; ++kk)                       \
              acc[(MH)*4 + mq][(NP)*2 + np] =                                    \
      __builtin_amdgcn_mfma_f32_16x16x32_bf16(aa[mq][kk], bb[np][kk],            \
                                              acc[(MH)*4 + mq][(NP)*2 + np],     \
                                              0, 0, 0)

#define MFMA_WRAP(X)                                                             \
  __builtin_amdgcn_s_barrier();                                                  \
  __builtin_amdgcn_s_setprio(1);                                                 \
  X;                                                                             \
  __builtin_amdgcn_s_setprio(0);                                                 \
  __builtin_amdgcn_s_barrier()

  // Prologue: stage tile 0's 4 halves + A0(1), oldest-first (matches ledger).
  {
    int bcol0 = (bcg * 16) << 8;
    STAGE_HALF(As, P, brow, 0, 0, 0);    // A0(0)
    STAGE_HALF(Bs, T, bcol0, 0, 0, 0);   // B0(0)
    STAGE_HALF(As, P, brow, 0, 1, 0);    // A1(0)
    STAGE_HALF(Bs, T, bcol0, 0, 1, 0);   // B1(0)
    STAGE_HALF(As, P, brow, 1, 0, 64);   // A0(1)
  }

#pragma unroll 1
  for (int j = 0; j < 16; ++j) {
    int bcol = (bcg * 16 + j) << 8;
#pragma unroll
    for (int kt = 0; kt < 8; ++kt) {
      const int g = j * 8 + kt;          // global K-tile index 0..127
      const int CB = kt & 1;             // current dbuf
      const int NB = (kt + 1) & 1;       // next dbuf
      const int KC1 = ((kt + 1) & 7) * 64;
      const int KC2 = ((kt + 2) & 7) * 64;
      int bcolT = (bcg * 16 + j + ((kt + 1) >> 3)) << 8;  // tile (g+1)'s bcol
      bf16x8 a0[4][2], a1[4][2], b0[2][2], b1[2][2], b0r[2][2];

      // ---- p1: wait(all 4 halves of g landed), Q(0,0) ----
      if (g == 127) asm volatile("s_waitcnt vmcnt(0)" ::: "memory");
      else          asm volatile("s_waitcnt vmcnt(2)" ::: "memory");
      RD_A(a0, CB, 0);
      RD_B(b0, CB, 0);
      if (g < 127) STAGE_HALF(Bs, T, bcolT, NB, 0, KC1);  // B0(g+1)
      MFMA_WRAP(MM_Q(0, 0, a0, b0));
      // ---- p2: Q(0,1), reuse a0 ----
      RD_B(b1, CB, 1);
      if (g < 127) STAGE_HALF(As, P, brow, NB, 1, KC1);   // A1(g+1)
      MFMA_WRAP(MM_Q(0, 1, a0, b1));
      // ---- p3: Q(1,1), reuse b1 ----
      RD_A(a1, CB, 1);
      if (g < 127) STAGE_HALF(Bs, T, bcolT, NB, 1, KC1);  // B1(g+1)
      MFMA_WRAP(MM_Q(1, 1, a1, b1));
      // ---- p4: Q(1,0), re-read b0 ----
      RD_B(b0r, CB, 0);
      if (g < 126) STAGE_HALF(As, P, brow, CB, 0, KC2);   // A0(g+2)
      MFMA_WRAP(MM_Q(1, 0, a1, b0r));
    }

    // Epilogue for tile (brow, bcol) — overlaps next tile's in-flight stages.
#pragma unroll
    for (int m = 0; m < 8; ++m)
#pragma unroll
      for (int n = 0; n < 4; ++n)
#pragma unroll
        for (int jj = 0; jj < 4; ++jj) {
          float logit = acc[m][n][jj] * INV_T;
          int grow = brow + wr + m * 16 + rlane * 4 + jj;
          int gcol = bcol + wc + n * 16 + clane;
          if (grow == gcol) diag[grow] = logit;
          acc[m][n][jj] = __expf(logit);
        }
#pragma unroll
    for (int m = 0; m < 8; ++m)
#pragma unroll
      for (int jj = 0; jj < 4; ++jj) {
        float rs = acc[m][0][jj] + acc[m][1][jj] + acc[m][2][jj] + acc[m][3][jj];
        rs += __shfl_xor(rs, 1);
        rs += __shfl_xor(rs, 2);
        rs += __shfl_xor(rs, 4);
        rs += __shfl_xor(rs, 8);
        if (clane == 0) atomicAdd(&row_sum[brow + wr + m * 16 + rlane * 4 + jj], rs);
      }
#pragma unroll
    for (int n = 0; n < 4; ++n) {
      float cs = 0.f;
#pragma unroll
      for (int m = 0; m < 8; ++m)
#pragma unroll
        for (int jj = 0; jj < 4; ++jj) cs += acc[m][n][jj];
      cs += __shfl_xor(cs, 16);
      cs += __shfl_xor(cs, 32);
      if (rlane == 0) atomicAdd(&col_sum[bcol + wc + n * 16 + clane], cs);
    }
#pragma unroll
    for (int m = 0; m < 8; ++m)
#pragma unroll
      for (int n = 0; n < 4; ++n) acc[m][n] = (f32x4){0.f, 0.f, 0.f, 0.f};
  }
#undef STAGE_HALF
#undef RD_A
#undef RD_B
#undef MM_Q
#undef MFMA_WRAP
}

__global__ __launch_bounds__(256) void finalize_kernel(const float* __restrict__ rs,
                                                       const float* __restrict__ cs,
                                                       const float* __restrict__ dg,
                                                       float* __restrict__ out) {
  float s = 0.f;
  for (int i = threadIdx.x; i < B_DIM; i += 256)
    s += 0.5f * (logf(rs[i]) + logf(cs[i])) - dg[i];
#pragma unroll
  for (int m = 1; m < 64; m <<= 1) s += __shfl_xor(s, m);
  __shared__ float red[4];
  if ((threadIdx.x & 63) == 0) red[threadIdx.x >> 6] = s;
  __syncthreads();
  if (threadIdx.x == 0)
    out[0] = (red[0] + red[1] + red[2] + red[3]) * (1.0f / (float)B_DIM);
}

extern "C" void kernel_launch(void* const* d_in, const int* in_sizes, int n_in,
                              void* d_out, int out_size, void* d_ws, size_t ws_size,
                              hipStream_t stream) {
  const float* p = (const float*)d_in[0];
  const float* t = (const float*)d_in[1];
  float* out = (float*)d_out;

  char* ws = (char*)d_ws;
  const size_t embBytes = (size_t)B_DIM * D_DIM * sizeof(uint16_t);  // 16 MB
  uint16_t* Pn = (uint16_t*)ws;
  uint16_t* Tn = (uint16_t*)(ws + embBytes);
  float* row_sum = (float*)(ws + 2 * embBytes);
  float* col_sum = row_sum + B_DIM;
  float* diag = col_sum + B_DIM;

  hipMemsetAsync(row_sum, 0, 2 * (size_t)B_DIM * sizeof(float), stream);
  normalize_kernel<<<B_DIM / 4, 256, 0, stream>>>(p, Pn);
  normalize_kernel<<<B_DIM / 4, 256, 0, stream>>>(t, Tn);
  infonce_main<<<256, 512, 0, stream>>>(Pn, Tn, row_sum, col_sum, diag);
  finalize_kernel<<<1, 256, 0, stream>>>(row_sum, col_sum, diag, out);
}